// Round 2
// baseline (384.526 us; speedup 1.0000x reference)
//
#include <hip/hip_runtime.h>
#include <hip/hip_bf16.h>
#include <cstdint>
#include <cstddef>

// TripletLoss: inputs (8192,128) fp32, targets (8192,) int32, 64 classes.
// out[0] = loss, out[1..] = dist (8192x8192) row-major fp32.
// R2: LDS-free dist kernel. Operand rows are 256B; the MFMA fragment load
// pattern (16 rows x 16B at 64B-aligned offsets) is fully 64B-coalesced
// straight from global, and Xb (2MB) is L2-resident. Removing LDS removes
// the staging vmcnt(0)+barrier drain and lifts occupancy 2->3 blocks/CU.
// Loss kernel rewritten multi-wave + unrolled (old one was a rolled
// single-block latency chain).

#define NROWS 8192
#define DIMK  128
#define MARGIN 0.3f

typedef __bf16 bf16x8 __attribute__((ext_vector_type(8)));
typedef float  f32x4  __attribute__((ext_vector_type(4)));
typedef int    i32x4  __attribute__((ext_vector_type(4)));
typedef float  f32x2  __attribute__((ext_vector_type(2)));

__device__ __forceinline__ unsigned short f2bf(float f) {
    unsigned u = __float_as_uint(f);
    u += 0x7fffu + ((u >> 16) & 1u);
    return (unsigned short)(u >> 16);
}

// prep: fp32 -> bf16 (RNE) into ws, row sq-norms from the ROUNDED values
// (keeps the diagonal sqd ~0), init ap/an reduction arrays.
__global__ __launch_bounds__(256) void prep_kernel(
    const float* __restrict__ X, unsigned short* __restrict__ Xb,
    float* __restrict__ sq, int* __restrict__ ap, int* __restrict__ an)
{
    const int t = blockIdx.x * 256 + threadIdx.x;
    if (t < NROWS) { ap[t] = 0; an[t] = 0x7f800000; }  // 0.0f / +inf
    const int row  = t >> 6;
    const int lane = t & 63;
    const f32x2 v = *(const f32x2*)(X + (size_t)row * DIMK + lane * 2);
    const unsigned short b0 = f2bf(v[0]);
    const unsigned short b1 = f2bf(v[1]);
    *(unsigned*)(Xb + (size_t)row * DIMK + lane * 2) =
        (unsigned)b0 | ((unsigned)b1 << 16);
    const float f0 = __uint_as_float((unsigned)b0 << 16);
    const float f1 = __uint_as_float((unsigned)b1 << 16);
    float s = f0 * f0 + f1 * f1;
    #pragma unroll
    for (int off = 32; off; off >>= 1) s += __shfl_xor(s, off);
    if (lane == 0) sq[row] = s;
}

// dist kernel: 128x128 tile per block (grid 64x64), 4 waves of 64x64 via
// 4x4 grid of 16x16x32 bf16 MFMA. No LDS: fragments loaded directly from
// global (L2-resident, fully coalesced at 64B granularity).
__global__ __launch_bounds__(256, 3) void dist_kernel(
    const unsigned short* __restrict__ Xb, const float* __restrict__ sq,
    const int* __restrict__ tgt, float* __restrict__ dist,
    int* __restrict__ ap, int* __restrict__ an)
{
    const int t  = threadIdx.x;
    const int bm = blockIdx.x, bn = blockIdx.y;

    const int lane = t & 63, wave = t >> 6;
    const int wm = (wave >> 1) * 64, wn = (wave & 1) * 64;
    const int l15 = lane & 15, quad = lane >> 4;

    const int rbase = bm * 128 + wm;   // this wave's 64 output rows
    const int cbase = bn * 128 + wn;   // this wave's 64 output cols

    f32x4 acc[4][4];
    #pragma unroll
    for (int mi = 0; mi < 4; mi++)
        #pragma unroll
        for (int ni = 0; ni < 4; ni++)
            acc[mi][ni] = (f32x4){0.f, 0.f, 0.f, 0.f};

    // ---- MFMA K loop: 4 k-steps of 32, operands straight from global ----
    // A operand lane layout: A[m = lane&15][k = quad*8 + j] -> row
    // (rbase+mi*16+l15), bytes [ks*64 + quad*16, +16). 16 rows x 64B full
    // coalescing per load instruction. Same for B.
    #pragma unroll
    for (int ks = 0; ks < 4; ks++) {
        const int kb = ks * 32 + quad * 8;
        bf16x8 a_frag[4], b_frag[4];
        #pragma unroll
        for (int mi = 0; mi < 4; mi++)
            a_frag[mi] = *(const bf16x8*)(Xb + (size_t)(rbase + mi * 16 + l15) * DIMK + kb);
        #pragma unroll
        for (int ni = 0; ni < 4; ni++)
            b_frag[ni] = *(const bf16x8*)(Xb + (size_t)(cbase + ni * 16 + l15) * DIMK + kb);
        #pragma unroll
        for (int mi = 0; mi < 4; mi++)
            #pragma unroll
            for (int ni = 0; ni < 4; ni++)
                acc[mi][ni] = __builtin_amdgcn_mfma_f32_16x16x32_bf16(
                    a_frag[mi], b_frag[ni], acc[mi][ni], 0, 0, 0);
    }

    // ---- epilogue: sqd -> dist, store, fused per-row max/min ----
    // C/D layout: col = lane&15, row = quad*4 + reg (per frag).
    const float INF = __int_as_float(0x7f800000);

    float sqc[4]; int tc[4]; int cg[4];
    #pragma unroll
    for (int ni = 0; ni < 4; ni++) {
        cg[ni]  = cbase + ni * 16 + l15;
        sqc[ni] = sq[cg[ni]];
        tc[ni]  = tgt[cg[ni]];
    }

    #pragma unroll
    for (int mi = 0; mi < 4; mi++) {
        const int rg0 = rbase + mi * 16 + quad * 4;      // 16B aligned
        const f32x4 sqr = *(const f32x4*)(sq + rg0);
        const i32x4 tr  = *(const i32x4*)(tgt + rg0);
        #pragma unroll
        for (int reg = 0; reg < 4; reg++) {
            const int rg = rg0 + reg;
            float apv = -1.0f, anv = INF;
            #pragma unroll
            for (int ni = 0; ni < 4; ni++) {
                const float dot = acc[mi][ni][reg];
                float sqd = sqr[reg] + sqc[ni] - 2.0f * dot;
                float d = sqd > 0.0f ? sqrtf(sqd) : 0.0f;
                if (rg == cg[ni]) d = 0.0f;              // exact diagonal
                __builtin_nontemporal_store(d, dist + (size_t)rg * NROWS + cg[ni]);
                const bool same = (tr[reg] == tc[ni]);
                apv = fmaxf(apv, same ? d : -1.0f);
                anv = fminf(anv, same ? INF : d);
            }
            // reduce across the 16 lanes of this quad group (cols)
            #pragma unroll
            for (int m = 1; m < 16; m <<= 1) {
                apv = fmaxf(apv, __shfl_xor(apv, m));
                anv = fminf(anv, __shfl_xor(anv, m));
            }
            // one lane per row commits; int compare == float compare for >=0
            if (l15 == mi * 4 + reg) {
                atomicMax(ap + rg, __float_as_int(apv));
                atomicMin(an + rg, __float_as_int(anv));
            }
        }
    }
}

// loss: 1024 threads, fully unrolled (8 elems/thread, 16 loads in flight),
// wave shuffle + LDS combine.
__global__ __launch_bounds__(1024) void loss_kernel(
    const int* __restrict__ ap, const int* __restrict__ an,
    float* __restrict__ out)
{
    __shared__ float red[16];
    float s = 0.0f;
    #pragma unroll
    for (int i = 0; i < 8; i++) {
        const int idx = i * 1024 + threadIdx.x;
        const float v = __int_as_float(ap[idx]) - __int_as_float(an[idx]) + MARGIN;
        s += v > 0.0f ? v : 0.0f;
    }
    #pragma unroll
    for (int off = 32; off; off >>= 1) s += __shfl_xor(s, off);
    if ((threadIdx.x & 63) == 0) red[threadIdx.x >> 6] = s;
    __syncthreads();
    if (threadIdx.x < 64) {
        float v = (threadIdx.x < 16) ? red[threadIdx.x] : 0.0f;
        #pragma unroll
        for (int off = 8; off; off >>= 1) v += __shfl_xor(v, off);
        if (threadIdx.x == 0) out[0] = v * (1.0f / NROWS);
    }
}

extern "C" void kernel_launch(void* const* d_in, const int* in_sizes, int n_in,
                              void* d_out, int out_size, void* d_ws, size_t ws_size,
                              hipStream_t stream)
{
    const float* X   = (const float*)d_in[0];
    const int*   tgt = (const int*)d_in[1];
    float*       out = (float*)d_out;

    // ws layout: Xb bf16 8192x128 (2 MB) | sq (32 KB) | ap (32 KB) | an (32 KB)
    unsigned short* Xb = (unsigned short*)d_ws;
    float* sq = (float*)((char*)d_ws + (size_t)NROWS * DIMK * 2);
    int*   ap = (int*)(sq + NROWS);
    int*   an = ap + NROWS;

    prep_kernel<<<(NROWS * 64) / 256, 256, 0, stream>>>(X, Xb, sq, ap, an);

    dim3 grid(64, 64);
    dist_kernel<<<grid, 256, 0, stream>>>(Xb, sq, tgt, out + 1, ap, an);

    loss_kernel<<<1, 1024, 0, stream>>>(ap, an, out);
}

// Round 3
// 377.125 us; speedup vs baseline: 1.0196x; 1.0196x over previous
//
#include <hip/hip_runtime.h>
#include <hip/hip_bf16.h>
#include <cstdint>
#include <cstddef>

// TripletLoss: inputs (8192,128) fp32, targets (8192,) int32, 64 classes.
// out[0] = loss, out[1..] = dist (8192x8192) row-major fp32.
// R3: store-path fix. R2 showed writes at 2.2 TB/s (27% peak) with 1.45x
// write amplification: nontemporal dword stores + 4B-misaligned dist base
// (out+1) streamed split sub-line granules to HBM. Changes:
//   - plain (cached) stores: L2 merges into full dirty lines before drain
//   - 32x512 tile (was 128x128): 2KB contiguous per row instead of 512B;
//     bn-fast grid order so 16 consecutive blocks cover a 1MB row-band
//   - block-level LDS combine of ap/an -> 4x fewer global atomics

#define NROWS 8192
#define DIMK  128
#define MARGIN 0.3f

typedef __bf16 bf16x8 __attribute__((ext_vector_type(8)));
typedef float  f32x4  __attribute__((ext_vector_type(4)));
typedef int    i32x4  __attribute__((ext_vector_type(4)));
typedef float  f32x2  __attribute__((ext_vector_type(2)));

__device__ __forceinline__ unsigned short f2bf(float f) {
    unsigned u = __float_as_uint(f);
    u += 0x7fffu + ((u >> 16) & 1u);
    return (unsigned short)(u >> 16);
}

// prep: fp32 -> bf16 (RNE) into ws, row sq-norms from the ROUNDED values
// (keeps the diagonal sqd ~0), init ap/an reduction arrays.
__global__ __launch_bounds__(256) void prep_kernel(
    const float* __restrict__ X, unsigned short* __restrict__ Xb,
    float* __restrict__ sq, int* __restrict__ ap, int* __restrict__ an)
{
    const int t = blockIdx.x * 256 + threadIdx.x;
    if (t < NROWS) { ap[t] = 0; an[t] = 0x7f800000; }  // 0.0f / +inf
    const int row  = t >> 6;
    const int lane = t & 63;
    const f32x2 v = *(const f32x2*)(X + (size_t)row * DIMK + lane * 2);
    const unsigned short b0 = f2bf(v[0]);
    const unsigned short b1 = f2bf(v[1]);
    *(unsigned*)(Xb + (size_t)row * DIMK + lane * 2) =
        (unsigned)b0 | ((unsigned)b1 << 16);
    const float f0 = __uint_as_float((unsigned)b0 << 16);
    const float f1 = __uint_as_float((unsigned)b1 << 16);
    float s = f0 * f0 + f1 * f1;
    #pragma unroll
    for (int off = 32; off; off >>= 1) s += __shfl_xor(s, off);
    if (lane == 0) sq[row] = s;
}

// dist kernel: 32x512 output tile per block; grid (bn=16, bm=256), bn fast.
// 4 waves: wave w covers all 32 rows x cols [w*128, w*128+128) via a 2x8
// grid of 16x16x32 bf16 MFMA. Operands straight from L2-resident Xb.
__global__ __launch_bounds__(256, 3) void dist_kernel(
    const unsigned short* __restrict__ Xb, const float* __restrict__ sq,
    const int* __restrict__ tgt, float* __restrict__ dist,
    int* __restrict__ ap, int* __restrict__ an)
{
    __shared__ int ap_s[32], an_s[32];

    const int t = threadIdx.x;
    if (t < 32) { ap_s[t] = 0; an_s[t] = 0x7f800000; }
    __syncthreads();

    const int bn = blockIdx.x, bm = blockIdx.y;
    const int lane = t & 63, wave = t >> 6;
    const int l15 = lane & 15, quad = lane >> 4;

    const int rbase = bm * 32;                 // block's 32 rows
    const int cbase = bn * 512 + wave * 128;   // this wave's 128 cols

    f32x4 acc[2][8];
    #pragma unroll
    for (int mi = 0; mi < 2; mi++)
        #pragma unroll
        for (int ni = 0; ni < 8; ni++)
            acc[mi][ni] = (f32x4){0.f, 0.f, 0.f, 0.f};

    // ---- MFMA K loop: 4 k-steps of 32, operands from global (L2) ----
    // A operand lane layout: A[m = lane&15][k = quad*8 + j].
    #pragma unroll
    for (int ks = 0; ks < 4; ks++) {
        const int kb = ks * 32 + quad * 8;
        bf16x8 a_frag[2], b_frag[8];
        #pragma unroll
        for (int mi = 0; mi < 2; mi++)
            a_frag[mi] = *(const bf16x8*)(Xb + (size_t)(rbase + mi * 16 + l15) * DIMK + kb);
        #pragma unroll
        for (int ni = 0; ni < 8; ni++)
            b_frag[ni] = *(const bf16x8*)(Xb + (size_t)(cbase + ni * 16 + l15) * DIMK + kb);
        #pragma unroll
        for (int mi = 0; mi < 2; mi++)
            #pragma unroll
            for (int ni = 0; ni < 8; ni++)
                acc[mi][ni] = __builtin_amdgcn_mfma_f32_16x16x32_bf16(
                    a_frag[mi], b_frag[ni], acc[mi][ni], 0, 0, 0);
    }

    // ---- epilogue: sqd -> dist, cached stores, fused per-row max/min ----
    // C/D layout: col = lane&15, row = quad*4 + reg (per frag).
    const float INF = __int_as_float(0x7f800000);

    float sqc[8]; int tc[8]; int cg[8];
    #pragma unroll
    for (int ni = 0; ni < 8; ni++) {
        cg[ni]  = cbase + ni * 16 + l15;
        sqc[ni] = sq[cg[ni]];
        tc[ni]  = tgt[cg[ni]];
    }

    #pragma unroll
    for (int mi = 0; mi < 2; mi++) {
        const int rg0 = rbase + mi * 16 + quad * 4;      // 16B aligned
        const f32x4 sqr = *(const f32x4*)(sq + rg0);
        const i32x4 tr  = *(const i32x4*)(tgt + rg0);
        #pragma unroll
        for (int reg = 0; reg < 4; reg++) {
            const int rg = rg0 + reg;
            float* drow = dist + (size_t)rg * NROWS;
            float apv = -1.0f, anv = INF;
            #pragma unroll
            for (int ni = 0; ni < 8; ni++) {
                const float dot = acc[mi][ni][reg];
                float sqd = sqr[reg] + sqc[ni] - 2.0f * dot;
                float d = sqd > 0.0f ? sqrtf(sqd) : 0.0f;
                if (rg == cg[ni]) d = 0.0f;              // exact diagonal
                drow[cg[ni]] = d;                        // cached store: L2 merges lines
                const bool same = (tr[reg] == tc[ni]);
                apv = fmaxf(apv, same ? d : -1.0f);
                anv = fminf(anv, same ? INF : d);
            }
            // reduce across the 16 lanes of this quad group (cols)
            #pragma unroll
            for (int m = 1; m < 16; m <<= 1) {
                apv = fmaxf(apv, __shfl_xor(apv, m));
                anv = fminf(anv, __shfl_xor(anv, m));
            }
            // int compare == float compare for the value ranges used here
            if (l15 == 0) {
                atomicMax(&ap_s[mi * 16 + quad * 4 + reg], __float_as_int(apv));
                atomicMin(&an_s[mi * 16 + quad * 4 + reg], __float_as_int(anv));
            }
        }
    }

    __syncthreads();
    if (t < 32) {
        atomicMax(ap + rbase + t, ap_s[t]);
        atomicMin(an + rbase + t, an_s[t]);
    }
}

// loss: 1024 threads, fully unrolled, wave shuffle + LDS combine.
__global__ __launch_bounds__(1024) void loss_kernel(
    const int* __restrict__ ap, const int* __restrict__ an,
    float* __restrict__ out)
{
    __shared__ float red[16];
    float s = 0.0f;
    #pragma unroll
    for (int i = 0; i < 8; i++) {
        const int idx = i * 1024 + threadIdx.x;
        const float v = __int_as_float(ap[idx]) - __int_as_float(an[idx]) + MARGIN;
        s += v > 0.0f ? v : 0.0f;
    }
    #pragma unroll
    for (int off = 32; off; off >>= 1) s += __shfl_xor(s, off);
    if ((threadIdx.x & 63) == 0) red[threadIdx.x >> 6] = s;
    __syncthreads();
    if (threadIdx.x < 64) {
        float v = (threadIdx.x < 16) ? red[threadIdx.x] : 0.0f;
        #pragma unroll
        for (int off = 8; off; off >>= 1) v += __shfl_xor(v, off);
        if (threadIdx.x == 0) out[0] = v * (1.0f / NROWS);
    }
}

extern "C" void kernel_launch(void* const* d_in, const int* in_sizes, int n_in,
                              void* d_out, int out_size, void* d_ws, size_t ws_size,
                              hipStream_t stream)
{
    const float* X   = (const float*)d_in[0];
    const int*   tgt = (const int*)d_in[1];
    float*       out = (float*)d_out;

    // ws layout: Xb bf16 8192x128 (2 MB) | sq (32 KB) | ap (32 KB) | an (32 KB)
    unsigned short* Xb = (unsigned short*)d_ws;
    float* sq = (float*)((char*)d_ws + (size_t)NROWS * DIMK * 2);
    int*   ap = (int*)(sq + NROWS);
    int*   an = ap + NROWS;

    prep_kernel<<<(NROWS * 64) / 256, 256, 0, stream>>>(X, Xb, sq, ap, an);

    dim3 grid(16, 256);   // bn fast: consecutive blocks cover one 1MB row-band
    dist_kernel<<<grid, 256, 0, stream>>>(Xb, sq, tgt, out + 1, ap, an);

    loss_kernel<<<1, 1024, 0, stream>>>(ap, an, out);
}